// Round 1
// baseline (246.876 us; speedup 1.0000x reference)
//
#include <hip/hip_runtime.h>

// fbm_dropout, fused single-kernel version.
//
// Semantics (unchanged from verified 2-kernel version): zero columns of an
// (8192, 4096) fp32 matrix whose 64x64 grid cell is touched by any of the
// 6400 fiber points of the current epoch.
//
// Exact-equivalence note: for p in [0,1), u = p*64.0f is exact (power-of-2
// scale), floor(u) exact, and f = u - floor(u) is exact in fp32. So the
// reference's  x_low <= p && p <= x_high  is bit-identical to
// 0.25f <= f && f <= 0.75f  with cell = (int)floor(u).
//
// Fusion rationale: the old build_mask_kernel ran on a single CU and gated
// the apply kernel behind a launch dependency (~15-20 us serial). Here every
// block recomputes the 16 KB mask in LDS (51.2 KB of fiber points, L2
// broadcast after the first blocks), then streams its share of the matrix.
// Grid stride (2048*256 float4s) is a multiple of the 1024 float4 columns,
// so each thread's mask float4 is loop-invariant and lives in registers.

#define N_COLS 4096
#define PTS_PER_EPOCH 100
#define N_GRID 64
#define TOTAL_PTS 10000
#define N_FIBERS 64
#define BLOCK 256
#define GRID_BLOCKS 2048   // 8 blocks/CU * 256 CUs -> all co-resident

__global__ __launch_bounds__(BLOCK) void fused_fbm_dropout(
    const float* __restrict__ fx,
    const float* __restrict__ fy,
    const int* __restrict__ epoch_p,
    const float4* __restrict__ in4,
    float4* __restrict__ out4,
    int n4) {
    __shared__ float mask[N_COLS];          // 16 KB
    const int tid = threadIdx.x;

    // init mask to 1.0
    for (int i = tid; i < N_COLS; i += BLOCK) mask[i] = 1.0f;
    __syncthreads();

    // ---- phase 1: build mask in LDS (every block, redundant, L2-cached) ----
    const int t = epoch_p[0] * PTS_PER_EPOCH;   // multiple of 4 -> float4 aligned
    // 64 fibers * 100 pts = 6400 points = 1600 float4 per axis.
    // Per fiber: 25 float4 groups. base float index f*10000 + t + j4*4 is a
    // multiple of 4, so float4 loads are 16B-aligned.
    for (int g = tid; g < (N_FIBERS * PTS_PER_EPOCH) / 4; g += BLOCK) {
        const int f  = g / 25;
        const int j4 = g - f * 25;
        const int base4 = (f * TOTAL_PTS + t) / 4 + j4;
        const float4 px4 = ((const float4*)fx)[base4];
        const float4 py4 = ((const float4*)fy)[base4];
        const float pxs[4] = {px4.x, px4.y, px4.z, px4.w};
        const float pys[4] = {py4.x, py4.y, py4.z, py4.w};
#pragma unroll
        for (int k = 0; k < 4; ++k) {
            const float ux = pxs[k] * 64.0f;
            const float uy = pys[k] * 64.0f;
            const float gxf = floorf(ux);
            const float gyf = floorf(uy);
            const float frx = ux - gxf;   // exact
            const float fry = uy - gyf;   // exact
            if (frx >= 0.25f && frx <= 0.75f && fry >= 0.25f && fry <= 0.75f) {
                const int gx = (int)gxf;
                const int gy = (int)gyf;
                if (gx >= 0 && gx < N_GRID && gy >= 0 && gy < N_GRID) {
                    // racing same-value LDS stores within the block: ok
                    mask[gy * N_GRID + gx] = 0.0f;
                }
            }
        }
    }
    __syncthreads();

    // ---- phase 2: streaming apply ----
    // stride = GRID_BLOCKS*BLOCK = 524288 = 512*1024 -> (i & 1023) is
    // loop-invariant per thread: hoist the mask float4 into registers.
    const int i0 = blockIdx.x * BLOCK + tid;
    const float4 m = ((const float4*)mask)[i0 & (N_COLS / 4 - 1)];
    const int stride = GRID_BLOCKS * BLOCK;
    for (int i = i0; i < n4; i += stride) {
        const float4 a = in4[i];
        float4 r;
        r.x = a.x * m.x;
        r.y = a.y * m.y;
        r.z = a.z * m.z;
        r.w = a.w * m.w;
        out4[i] = r;
    }
}

extern "C" void kernel_launch(void* const* d_in, const int* in_sizes, int n_in,
                              void* d_out, int out_size, void* d_ws, size_t ws_size,
                              hipStream_t stream) {
    const float* inp   = (const float*)d_in[0];   // (8192, 4096) fp32
    const float* fx    = (const float*)d_in[1];   // (64, 10000) fp32
    const float* fy    = (const float*)d_in[2];   // (64, 10000) fp32
    const int*   epoch = (const int*)d_in[3];     // scalar int

    const int n4 = out_size / 4;                  // 8,388,608 float4s
    fused_fbm_dropout<<<GRID_BLOCKS, BLOCK, 0, stream>>>(
        fx, fy, epoch, (const float4*)inp, (float4*)d_out, n4);
}